// Round 2
// baseline (9813.966 us; speedup 1.0000x reference)
//
#include <hip/hip_runtime.h>
#include <math.h>

#define HID    1024
#define G4     4096      // 4*HID gate rows per layer
#define VOC    32000
#define SEQL   64
#define BOSTOK 1
#define NTHR   512
#define NWAVES (NTHR / 64)       // 8 waves per block
#define NGRP   32                // barrier groups
#define BARW   4096              // ws words reserved for barrier state

struct P {
  const int*   src;
  const float* embE; const float* eWih; const float* eWhh; const float* ebih; const float* ebhh;
  const float* embD; const float* dWih; const float* dWhh; const float* dbih; const float* dbhh;
  const float* oW;   const float* ob;
  float* out;   // [64][32000] raw logits then log-probs
  float* ws;
};

// ---- device-coherent (agent-scope, relaxed) data movement ----
__device__ __forceinline__ float gld(const float* p) {
  return __hip_atomic_load((float*)p, __ATOMIC_RELAXED, __HIP_MEMORY_SCOPE_AGENT);
}
__device__ __forceinline__ void gst(float* p, float v) {
  __hip_atomic_store(p, v, __ATOMIC_RELAXED, __HIP_MEMORY_SCOPE_AGENT);
}
__device__ __forceinline__ int gldi(const int* p) {
  return __hip_atomic_load((int*)p, __ATOMIC_RELAXED, __HIP_MEMORY_SCOPE_AGENT);
}
__device__ __forceinline__ void gsti(int* p, int v) {
  __hip_atomic_store(p, v, __ATOMIC_RELAXED, __HIP_MEMORY_SCOPE_AGENT);
}

// ---- hierarchical reset-free grid barrier ----
// bar layout (unsigned words): top = bar[32]; grp[g] = bar[64 + 32*g] (g < NGRP);
// grpgen[g] = bar[2048 + 32*g]. Counters are MONOTONIC: at phase p the group
// target is p*grpsz, top target p*NGRP — no resets, no reset races. The final
// arriver release-stores p into all NGRP grpgen lines; each block spins only on
// its own group's line.
__device__ __forceinline__ void gridbar(unsigned* bar, unsigned phase, int g, unsigned grpsz) {
  __syncthreads();   // hipcc emits s_waitcnt vmcnt(0) lgkmcnt(0) before s_barrier
  if (threadIdx.x == 0) {
    __builtin_amdgcn_s_waitcnt(0);
    unsigned* grpc = bar + 64 + 32 * g;
    unsigned* topc = bar + 32;
    bool released = false;
    unsigned a = __hip_atomic_fetch_add(grpc, 1u, __ATOMIC_ACQ_REL, __HIP_MEMORY_SCOPE_AGENT);
    if (a == phase * grpsz - 1u) {         // last arriver in this group
      unsigned b = __hip_atomic_fetch_add(topc, 1u, __ATOMIC_ACQ_REL, __HIP_MEMORY_SCOPE_AGENT);
      if (b == phase * NGRP - 1u) {        // last group overall -> release
#pragma unroll
        for (int g2 = 0; g2 < NGRP; ++g2)
          __hip_atomic_store(bar + 2048 + 32 * g2, phase,
                             __ATOMIC_RELEASE, __HIP_MEMORY_SCOPE_AGENT);
        released = true;
      }
    }
    if (!released) {
      unsigned* gg = bar + 2048 + 32 * g;
      while (__hip_atomic_load(gg, __ATOMIC_RELAXED, __HIP_MEMORY_SCOPE_AGENT) < phase)
        __builtin_amdgcn_s_sleep(4);
      (void)__hip_atomic_load(gg, __ATOMIC_ACQUIRE, __HIP_MEMORY_SCOPE_AGENT);
    }
  }
  __syncthreads();
}

__device__ __forceinline__ float wsum(float v) {
#pragma unroll
  for (int o = 32; o > 0; o >>= 1) v += __shfl_xor(v, o, 64);
  return v;
}

// partial (unreduced) 1024-dot: global row w . LDS vector v  (order unchanged!)
__device__ __forceinline__ float dotg(const float* __restrict__ w, const float* v, int lane) {
  const float4* w4 = (const float4*)w;
  const float4* v4 = (const float4*)v;
  float acc = 0.f;
#pragma unroll
  for (int j = 0; j < 4; ++j) {
    float4 a = w4[lane + 64 * j];
    float4 b = v4[lane + 64 * j];
    acc += a.x * b.x + a.y * b.y + a.z * b.z + a.w * b.w;
  }
  return acc;
}

// LSTM elementwise: gates preact (4096, order i,f,g,o) + c_in -> h (LDS), optional c_out (global)
__device__ __forceinline__ void derive(const float* __restrict__ pa, const float* __restrict__ cin,
                                       float* __restrict__ cout, float* __restrict__ hout, int tid) {
  for (int i = tid; i < HID; i += NTHR) {
    float gi = gld(pa + i), gf = gld(pa + HID + i);
    float gg = gld(pa + 2 * HID + i), go = gld(pa + 3 * HID + i);
    float c  = cin ? gld(cin + i) : 0.f;
    float si = 1.f / (1.f + expf(-gi));
    float sf = 1.f / (1.f + expf(-gf));
    float so = 1.f / (1.f + expf(-go));
    float cn = sf * c + si * tanhf(gg);
    hout[i] = so * tanhf(cn);
    if (cout) gst(cout + i, cn);
  }
}

__device__ __forceinline__ void zerov(float* h, int tid) {
  for (int i = tid; i < HID; i += NTHR) h[i] = 0.f;
}

__global__ void init_bar(unsigned* bar) {
  for (int i = threadIdx.x; i < BARW; i += 256) bar[i] = 0;
}

__global__ void __launch_bounds__(NTHR, 8) rnn_all(P p) {
  const int  tid   = threadIdx.x;
  const int  lane  = tid & 63;
  const int  wv    = tid >> 6;
  const int  nblk  = gridDim.x;               // 256 / 512 / 1024
  const int  totw  = nblk * NWAVES;
  const int  gw    = blockIdx.x * NWAVES + wv;
  const int  grp   = blockIdx.x & (NGRP - 1);
  const unsigned grpsz = (unsigned)(nblk / NGRP);
  const bool b0    = (blockIdx.x == 0);
  unsigned   ph    = 0;
  unsigned*  bar   = (unsigned*)p.ws;

  __shared__ __align__(16) float sx[HID];
  __shared__ __align__(16) float sh0[HID];
  __shared__ __align__(16) float sh1[HID];
  __shared__ float rv[NWAVES];
  __shared__ int   ri[NWAVES];
  __shared__ int   stok;

  // ---- workspace layout (barrier words occupy ws[0..BARW-1]) ----
  float* pa0e = p.ws + BARW;       // 4 * G4
  float* pa1e = pa0e + 4 * G4;
  float* pa0d = pa1e + 4 * G4;
  float* pa1d = pa0d + 4 * G4;
  float* c0e  = pa1d + 4 * G4;     // 4 * HID each; slot s&3 = c entering step s
  float* c1e  = c0e + 4 * HID;
  float* c0d  = c1e + 4 * HID;
  float* c1d  = c0d + 4 * HID;
  float* B0   = c1d + 4 * HID;     // G4: Whh0d@h0 + biases for current dec step
  float* B1   = B0 + G4;           // G4
  float* pmv  = B1 + G4;           // up to 1024 per-block argmax partial values
  int*   pmi  = (int*)(pmv + 1024);
  float* lsep = (float*)(pmi + 1024); // 64 rows * (nblk/64) segs * 2 (m, s)

  const float* eW0i = p.eWih;  const float* eW1i = p.eWih + (size_t)G4 * HID;
  const float* eW0h = p.eWhh;  const float* eW1h = p.eWhh + (size_t)G4 * HID;
  const float* eb0i = p.ebih;  const float* eb1i = p.ebih + G4;
  const float* eb0h = p.ebhh;  const float* eb1h = p.ebhh + G4;
  const float* dW0i = p.dWih;  const float* dW1i = p.dWih + (size_t)G4 * HID;
  const float* dW0h = p.dWhh;  const float* dW1h = p.dWhh + (size_t)G4 * HID;
  const float* db0i = p.dbih;  const float* db1i = p.dbih + G4;
  const float* db0h = p.dbhh;  const float* db1h = p.dbhh + G4;

  // ================= encoder: skewed pipeline, phase k computes preact0(k) & preact1(k-1) =====
  for (int k = 0; k <= SEQL; ++k) {
    if (k < SEQL) {
      int tok = p.src[k];
      for (int i = tid; i < HID; i += NTHR) sx[i] = p.embE[(size_t)tok * HID + i];
    }
    if (k >= 1) {   // derive h0(k-1) from preact0(k-1); c entering step k-1
      derive(pa0e + ((k - 1) & 3) * G4,
             (k >= 2) ? (c0e + ((k - 1) & 3) * HID) : nullptr,
             b0 ? (c0e + (k & 3) * HID) : nullptr, sh0, tid);
    } else zerov(sh0, tid);
    if (k >= 2) {   // derive h1(k-2)
      derive(pa1e + ((k - 2) & 3) * G4,
             (k >= 3) ? (c1e + ((k - 2) & 3) * HID) : nullptr,
             b0 ? (c1e + ((k - 1) & 3) * HID) : nullptr, sh1, tid);
    } else zerov(sh1, tid);
    __syncthreads();

    for (int it = gw; it < 2 * G4; it += totw) {
      if (it < G4) {
        if (k < SEQL) {
          int r = it;
          float a = dotg(eW0i + (size_t)r * HID, sx, lane) +
                    dotg(eW0h + (size_t)r * HID, sh0, lane);
          float v = wsum(a) + eb0i[r] + eb0h[r];
          if (lane == 0) gst(pa0e + (k & 3) * G4 + r, v);
        }
      } else if (k >= 1) {
        int r = it - G4;
        float a = dotg(eW1i + (size_t)r * HID, sh0, lane) +
                  dotg(eW1h + (size_t)r * HID, sh1, lane);
        float v = wsum(a) + eb1i[r] + eb1h[r];
        if (lane == 0) gst(pa1e + ((k - 1) & 3) * G4 + r, v);
      }
    }
    gridbar(bar, ++ph, grp, grpsz);
  }

  // ================= decoder init: B0/B1 for step 0 from encoder final state ==================
  {
    derive(pa0e + (63 & 3) * G4, c0e + (63 & 3) * HID, b0 ? (c0d + 0) : nullptr, sh0, tid);
    derive(pa1e + (63 & 3) * G4, c1e + (63 & 3) * HID, b0 ? (c1d + 0) : nullptr, sh1, tid);
    __syncthreads();
    for (int it = gw; it < 2 * G4; it += totw) {
      if (it < G4) {
        int r = it;
        float v = wsum(dotg(dW0h + (size_t)r * HID, sh0, lane)) + db0i[r] + db0h[r];
        if (lane == 0) gst(B0 + r, v);
      } else {
        int r = it - G4;
        float v = wsum(dotg(dW1h + (size_t)r * HID, sh1, lane)) + db1i[r] + db1h[r];
        if (lane == 0) gst(B1 + r, v);
      }
    }
    gridbar(bar, ++ph, grp, grpsz);
  }

  // ================= decoder: 3 phases per step ===============================================
  for (int t = 0; t < SEQL; ++t) {
    // ---- Ph1: token select (redundant per block) + preact0(t) = Wih0d@x + B0 ----
    if (t == 0) {
      if (tid == 0) stok = BOSTOK;
    } else if (wv == 0) {
      float bv = -1e30f; int bi = 0;
      for (int idx = lane; idx < nblk; idx += 64) {
        float v  = gld(pmv + idx);
        int   i2 = gldi(pmi + idx);
        if (v > bv || (v == bv && i2 < bi)) { bv = v; bi = i2; }
      }
#pragma unroll
      for (int o = 32; o > 0; o >>= 1) {
        float v  = __shfl_xor(bv, o, 64);
        int   i2 = __shfl_xor(bi, o, 64);
        if (v > bv || (v == bv && i2 < bi)) { bv = v; bi = i2; }
      }
      if (lane == 0) stok = bi;
    }
    __syncthreads();
    {
      int tok = stok;
      for (int i = tid; i < HID; i += NTHR) sx[i] = p.embD[(size_t)tok * HID + i];
    }
    __syncthreads();
    for (int it = gw; it < G4; it += totw) {
      float v = wsum(dotg(dW0i + (size_t)it * HID, sx, lane)) + gld(B0 + it);
      if (lane == 0) gst(pa0d + (t & 3) * G4 + it, v);
    }
    gridbar(bar, ++ph, grp, grpsz);

    // ---- Ph2: h0d(t); preact1(t) = Wih1d@h0 + B1 ----
    derive(pa0d + (t & 3) * G4, c0d + (t & 3) * HID,
           b0 ? (c0d + ((t + 1) & 3) * HID) : nullptr, sh0, tid);
    __syncthreads();
    for (int it = gw; it < G4; it += totw) {
      float v = wsum(dotg(dW1i + (size_t)it * HID, sh0, lane)) + gld(B1 + it);
      if (lane == 0) gst(pa1d + (t & 3) * G4 + it, v);
    }
    gridbar(bar, ++ph, grp, grpsz);

    // ---- Ph3: h1d(t); logits = outW@h1 + b (+argmax partials); B0/B1 for step t+1 ----
    derive(pa1d + (t & 3) * G4, c1d + (t & 3) * HID,
           b0 ? (c1d + ((t + 1) & 3) * HID) : nullptr, sh1, tid);
    __syncthreads();
    float bv = -1e30f; int bi = 0;
    for (int it = gw; it < VOC + 2 * G4; it += totw) {
      if (it < VOC) {
        float v = wsum(dotg(p.oW + (size_t)it * HID, sh1, lane)) + p.ob[it];
        if (lane == 0) gst(p.out + (size_t)t * VOC + it, v);
        if (v > bv) { bv = v; bi = it; }   // rows increase per wave -> first-max tie-break
      } else if (it < VOC + G4) {
        int r = it - VOC;
        float v = wsum(dotg(dW0h + (size_t)r * HID, sh0, lane)) + db0i[r] + db0h[r];
        if (lane == 0) gst(B0 + r, v);
      } else {
        int r = it - VOC - G4;
        float v = wsum(dotg(dW1h + (size_t)r * HID, sh1, lane)) + db1i[r] + db1h[r];
        if (lane == 0) gst(B1 + r, v);
      }
    }
    if (lane == 0) { rv[wv] = bv; ri[wv] = bi; }
    __syncthreads();
    if (tid == 0) {
      float v = rv[0]; int i2 = ri[0];
      for (int j = 1; j < NWAVES; ++j)
        if (rv[j] > v || (rv[j] == v && ri[j] < i2)) { v = rv[j]; i2 = ri[j]; }
      gst(pmv + blockIdx.x, v); gsti(pmi + blockIdx.x, i2);
    }
    gridbar(bar, ++ph, grp, grpsz);
  }

  // ================= epilogue: log_softmax over each of 64 rows (nblk/64 blocks per row) ======
  {
    const int spr  = nblk >> 6;                       // segments per row: 4 / 8 / 16
    const int lg   = (spr == 4) ? 2 : (spr == 8) ? 3 : 4;
    const int row  = blockIdx.x >> lg;
    const int seg  = blockIdx.x & (spr - 1);
    const int slen = VOC >> lg;                       // 8000 / 4000 / 2000
    float* base = p.out + (size_t)row * VOC + (size_t)seg * slen;

    float lm = -1e30f;
    for (int i = tid; i < slen; i += NTHR) lm = fmaxf(lm, gld(base + i));
#pragma unroll
    for (int o = 32; o > 0; o >>= 1) lm = fmaxf(lm, __shfl_xor(lm, o, 64));
    if (lane == 0) rv[wv] = lm;
    __syncthreads();
    float bm = rv[0];
#pragma unroll
    for (int j = 1; j < NWAVES; ++j) bm = fmaxf(bm, rv[j]);
    float ls = 0.f;
    for (int i = tid; i < slen; i += NTHR) ls += expf(gld(base + i) - bm);
    ls = wsum(ls);
    __syncthreads();
    if (lane == 0) rv[wv] = ls;
    __syncthreads();
    if (tid == 0) {
      float ss = 0.f;
      for (int j = 0; j < NWAVES; ++j) ss += rv[j];
      gst(lsep + blockIdx.x * 2,     bm);
      gst(lsep + blockIdx.x * 2 + 1, ss);
    }
    gridbar(bar, ++ph, grp, grpsz);

    const float* lp = lsep + (size_t)row * 2 * spr;
    float M = -1e30f;
    for (int j = 0; j < spr; ++j) M = fmaxf(M, gld(lp + 2 * j));
    float S = 0.f;
    for (int j = 0; j < spr; ++j) S += gld(lp + 2 * j + 1) * expf(gld(lp + 2 * j) - M);
    float L = M + logf(S);
    for (int i = tid; i < slen; i += NTHR) base[i] = gld(base + i) - L;
  }
}

extern "C" void kernel_launch(void* const* d_in, const int* in_sizes, int n_in,
                              void* d_out, int out_size, void* d_ws, size_t ws_size,
                              hipStream_t stream) {
  P p;
  p.src  = (const int*)d_in[0];
  // d_in[1] = tgt (only its length matters; == SEQL)
  p.embE = (const float*)d_in[2];
  p.eWih = (const float*)d_in[3];
  p.eWhh = (const float*)d_in[4];
  p.ebih = (const float*)d_in[5];
  p.ebhh = (const float*)d_in[6];
  p.embD = (const float*)d_in[7];
  p.dWih = (const float*)d_in[8];
  p.dWhh = (const float*)d_in[9];
  p.dbih = (const float*)d_in[10];
  p.dbhh = (const float*)d_in[11];
  p.oW   = (const float*)d_in[12];
  p.ob   = (const float*)d_in[13];
  p.out  = (float*)d_out;
  p.ws   = (float*)d_ws;

  // Pick the largest cooperative grid the runtime will accept (cached).
  static int g_nblk = 0;
  if (g_nblk == 0) {
    int dev = 0;
    (void)hipGetDevice(&dev);
    int ncu = 256;
    (void)hipDeviceGetAttribute(&ncu, hipDeviceAttributeMultiprocessorCount, dev);
    int maxb = 0;
    if (hipOccupancyMaxActiveBlocksPerMultiprocessor(&maxb, rnn_all, NTHR, 0) != hipSuccess
        || maxb < 1)
      maxb = 1;
    long cap = (long)maxb * (long)ncu;
    g_nblk = (cap >= 1024) ? 1024 : (cap >= 512) ? 512 : 256;
  }

  hipLaunchKernelGGL(init_bar, dim3(1), dim3(256), 0, stream, (unsigned*)d_ws);
  void* args[] = { &p };
  hipLaunchCooperativeKernel((const void*)rnn_all, dim3(g_nblk), dim3(NTHR), args, 0, stream);
}

// Round 3
// 7249.081 us; speedup vs baseline: 1.3538x; 1.3538x over previous
//
#include <hip/hip_runtime.h>
#include <hip/hip_fp16.h>
#include <math.h>

#define HID    1024
#define G4     4096      // 4*HID gate rows per layer
#define VOC    32000
#define SEQL   64
#define BOSTOK 1
#define NBLK   256
#define NTHR   1024
#define NWAVES (NTHR / 64)
#define TOTW   (NBLK * NWAVES)   // 4096 waves
#define NGRP   32                // barrier groups (8 blocks each)
#define GRPSZ  (NBLK / NGRP)
#define BARW   4096              // ws words reserved for barrier state
#define WSBASE 95232             // ws words used before the fp16 oW copy
#define NEEDH  (WSBASE * 4 + (size_t)VOC * HID * 2)   // bytes needed for fp16 path

struct P {
  const int*   src;
  const float* embE; const float* eWih; const float* eWhh; const float* ebih; const float* ebhh;
  const float* embD; const float* dWih; const float* dWhh; const float* dbih; const float* dbhh;
  const float* oW;   const float* ob;
  float* out;   // [64][32000] raw logits then log-probs
  float* ws;
  int useH;     // 1 -> ws holds fp16 copy of oW
};

// ---- device-coherent (agent-scope, relaxed) data movement ----
__device__ __forceinline__ float gld(const float* p) {
  return __hip_atomic_load((float*)p, __ATOMIC_RELAXED, __HIP_MEMORY_SCOPE_AGENT);
}
__device__ __forceinline__ void gst(float* p, float v) {
  __hip_atomic_store(p, v, __ATOMIC_RELAXED, __HIP_MEMORY_SCOPE_AGENT);
}
__device__ __forceinline__ int gldi(const int* p) {
  return __hip_atomic_load((int*)p, __ATOMIC_RELAXED, __HIP_MEMORY_SCOPE_AGENT);
}
__device__ __forceinline__ void gsti(int* p, int v) {
  __hip_atomic_store(p, v, __ATOMIC_RELAXED, __HIP_MEMORY_SCOPE_AGENT);
}

// ---- hierarchical reset-free grid barrier ----
// bar[32]=top counter; bar[64+32g]=group counter; bar[2048+32g]=group generation.
// Counters are MONOTONIC (targets phase*GRPSZ / phase*NGRP): no resets, no reset races.
__device__ __forceinline__ void gridbar(unsigned* bar, unsigned phase, int g) {
  __syncthreads();
  if (threadIdx.x == 0) {
    __builtin_amdgcn_s_waitcnt(0);   // all prior vmem complete
    unsigned* grpc = bar + 64 + 32 * g;
    unsigned* topc = bar + 32;
    bool released = false;
    unsigned a = __hip_atomic_fetch_add(grpc, 1u, __ATOMIC_ACQ_REL, __HIP_MEMORY_SCOPE_AGENT);
    if (a == phase * GRPSZ - 1u) {
      unsigned b = __hip_atomic_fetch_add(topc, 1u, __ATOMIC_ACQ_REL, __HIP_MEMORY_SCOPE_AGENT);
      if (b == phase * NGRP - 1u) {
#pragma unroll
        for (int g2 = 0; g2 < NGRP; ++g2)
          __hip_atomic_store(bar + 2048 + 32 * g2, phase,
                             __ATOMIC_RELEASE, __HIP_MEMORY_SCOPE_AGENT);
        released = true;
      }
    }
    if (!released) {
      unsigned* gg = bar + 2048 + 32 * g;
      while (__hip_atomic_load(gg, __ATOMIC_RELAXED, __HIP_MEMORY_SCOPE_AGENT) < phase)
        __builtin_amdgcn_s_sleep(4);
      (void)__hip_atomic_load(gg, __ATOMIC_ACQUIRE, __HIP_MEMORY_SCOPE_AGENT);
    }
  }
  __syncthreads();
}

__device__ __forceinline__ float wsum(float v) {
#pragma unroll
  for (int o = 32; o > 0; o >>= 1) v += __shfl_xor(v, o, 64);
  return v;
}

// partial (unreduced) 1024-dot: global fp32 row w . LDS vector v
__device__ __forceinline__ float dotg(const float* __restrict__ w, const float* v, int lane) {
  const float4* w4 = (const float4*)w;
  const float4* v4 = (const float4*)v;
  float acc = 0.f;
#pragma unroll
  for (int j = 0; j < 4; ++j) {
    float4 a = w4[lane + 64 * j];
    float4 b = v4[lane + 64 * j];
    acc += a.x * b.x + a.y * b.y + a.z * b.z + a.w * b.w;
  }
  return acc;
}

// 8 halves (one uint4) dot 8 floats
__device__ __forceinline__ float dot8(uint4 u, float4 b0, float4 b1) {
  float2 f; float acc;
  f = __half22float2(*reinterpret_cast<const __half2*>(&u.x));
  acc  = f.x * b0.x + f.y * b0.y;
  f = __half22float2(*reinterpret_cast<const __half2*>(&u.y));
  acc += f.x * b0.z + f.y * b0.w;
  f = __half22float2(*reinterpret_cast<const __half2*>(&u.z));
  acc += f.x * b1.x + f.y * b1.y;
  f = __half22float2(*reinterpret_cast<const __half2*>(&u.w));
  acc += f.x * b1.z + f.y * b1.w;
  return acc;
}

// LSTM elementwise: gates preact (4096, order i,f,g,o) + c_in -> h (LDS), optional c_out (global)
__device__ __forceinline__ void derive(const float* __restrict__ pa, const float* __restrict__ cin,
                                       float* __restrict__ cout, float* __restrict__ hout, int tid) {
  float gi = gld(pa + tid), gf = gld(pa + HID + tid);
  float gg = gld(pa + 2 * HID + tid), go = gld(pa + 3 * HID + tid);
  float c  = cin ? gld(cin + tid) : 0.f;
  float si = 1.f / (1.f + expf(-gi));
  float sf = 1.f / (1.f + expf(-gf));
  float so = 1.f / (1.f + expf(-go));
  float cn = sf * c + si * tanhf(gg);
  hout[tid] = so * tanhf(cn);
  if (cout) gst(cout + tid, cn);
}

__global__ void init_bar(unsigned* bar) {
  for (int i = threadIdx.x; i < BARW; i += 256) bar[i] = 0;
}

__global__ void __launch_bounds__(NTHR, 4) rnn_all(P p) {
  const int  tid  = threadIdx.x;
  const int  lane = tid & 63;
  const int  wv   = tid >> 6;
  const int  gw   = blockIdx.x * NWAVES + wv;
  const int  grp  = blockIdx.x & (NGRP - 1);
  const bool b0   = (blockIdx.x == 0);
  unsigned   ph   = 0;
  unsigned*  bar  = (unsigned*)p.ws;

  __shared__ __align__(16) float sx[HID];
  __shared__ __align__(16) float sh0[HID];
  __shared__ __align__(16) float sh1[HID];
  __shared__ float rv[NWAVES];
  __shared__ int   ri[NWAVES];
  __shared__ int   stok;

  // ---- workspace layout (barrier words occupy ws[0..BARW-1]) ----
  float* pa0e = p.ws + BARW;       // 4 * G4
  float* pa1e = pa0e + 4 * G4;
  float* pa0d = pa1e + 4 * G4;
  float* pa1d = pa0d + 4 * G4;
  float* c0e  = pa1d + 4 * G4;     // 4 * HID each; slot s&3 = c entering step s
  float* c1e  = c0e + 4 * HID;
  float* c0d  = c1e + 4 * HID;
  float* c1d  = c0d + 4 * HID;
  float* B0   = c1d + 4 * HID;     // G4: Whh0d@h0 + biases for current dec step
  float* B1   = B0 + G4;           // G4
  float* pmv  = B1 + G4;           // NBLK per-block argmax partial values
  int*   pmi  = (int*)(pmv + NBLK);
  float* lsep = (float*)(pmi + NBLK); // 64 rows * 4 segs * 2 (m, s)
  __half* oWh = (__half*)(p.ws + WSBASE);

  const float* eW0i = p.eWih;  const float* eW1i = p.eWih + (size_t)G4 * HID;
  const float* eW0h = p.eWhh;  const float* eW1h = p.eWhh + (size_t)G4 * HID;
  const float* eb0i = p.ebih;  const float* eb1i = p.ebih + G4;
  const float* eb0h = p.ebhh;  const float* eb1h = p.ebhh + G4;
  const float* dW0i = p.dWih;  const float* dW1i = p.dWih + (size_t)G4 * HID;
  const float* dW0h = p.dWhh;  const float* dW1h = p.dWhh + (size_t)G4 * HID;
  const float* db0i = p.dbih;  const float* db1i = p.dbih + G4;
  const float* db0h = p.dbhh;  const float* db1h = p.dbhh + G4;

  // ================= optional pre-pass: oW fp32 -> fp16 in workspace =========================
  if (p.useH) {
    const float4* s4 = (const float4*)p.oW;
    unsigned long long* d8 = (unsigned long long*)oWh;
    const size_t n4 = (size_t)VOC * HID / 4;
    for (size_t i = (size_t)blockIdx.x * NTHR + tid; i < n4; i += (size_t)NBLK * NTHR) {
      float4 f = s4[i];
      __half2 lo = __float22half2_rn(make_float2(f.x, f.y));
      __half2 hi = __float22half2_rn(make_float2(f.z, f.w));
      unsigned long long u =
          ((unsigned long long)(*reinterpret_cast<unsigned*>(&hi)) << 32) |
          (unsigned long long)(*reinterpret_cast<unsigned*>(&lo));
      // write-through (agent-scope) store: visible to all XCDs after gridbar
      __hip_atomic_store(d8 + i, u, __ATOMIC_RELAXED, __HIP_MEMORY_SCOPE_AGENT);
    }
    gridbar(bar, ++ph, grp);
  }

  // ================= encoder: skewed pipeline, phase k computes preact0(k) & preact1(k-1) =====
  for (int k = 0; k <= SEQL; ++k) {
    if (k < SEQL) {
      int tok = p.src[k];
      sx[tid] = p.embE[(size_t)tok * HID + tid];
    }
    if (k >= 1) {   // derive h0(k-1) from preact0(k-1); c entering step k-1
      derive(pa0e + ((k - 1) & 3) * G4,
             (k >= 2) ? (c0e + ((k - 1) & 3) * HID) : nullptr,
             b0 ? (c0e + (k & 3) * HID) : nullptr, sh0, tid);
    } else sh0[tid] = 0.f;
    if (k >= 2) {   // derive h1(k-2)
      derive(pa1e + ((k - 2) & 3) * G4,
             (k >= 3) ? (c1e + ((k - 2) & 3) * HID) : nullptr,
             b0 ? (c1e + ((k - 1) & 3) * HID) : nullptr, sh1, tid);
    } else sh1[tid] = 0.f;
    __syncthreads();

    for (int it = gw; it < 2 * G4; it += TOTW) {
      if (it < G4) {
        if (k < SEQL) {
          int r = it;
          float a = dotg(eW0i + (size_t)r * HID, sx, lane) +
                    dotg(eW0h + (size_t)r * HID, sh0, lane);
          float v = wsum(a) + eb0i[r] + eb0h[r];
          if (lane == 0) gst(pa0e + (k & 3) * G4 + r, v);
        }
      } else if (k >= 1) {
        int r = it - G4;
        float a = dotg(eW1i + (size_t)r * HID, sh0, lane) +
                  dotg(eW1h + (size_t)r * HID, sh1, lane);
        float v = wsum(a) + eb1i[r] + eb1h[r];
        if (lane == 0) gst(pa1e + ((k - 1) & 3) * G4 + r, v);
      }
    }
    gridbar(bar, ++ph, grp);
  }

  // ================= decoder init: B0/B1 for step 0 from encoder final state ==================
  {
    derive(pa0e + (63 & 3) * G4, c0e + (63 & 3) * HID, b0 ? (c0d + 0) : nullptr, sh0, tid);
    derive(pa1e + (63 & 3) * G4, c1e + (63 & 3) * HID, b0 ? (c1d + 0) : nullptr, sh1, tid);
    __syncthreads();
    for (int it = gw; it < 2 * G4; it += TOTW) {
      if (it < G4) {
        int r = it;
        float v = wsum(dotg(dW0h + (size_t)r * HID, sh0, lane)) + db0i[r] + db0h[r];
        if (lane == 0) gst(B0 + r, v);
      } else {
        int r = it - G4;
        float v = wsum(dotg(dW1h + (size_t)r * HID, sh1, lane)) + db1i[r] + db1h[r];
        if (lane == 0) gst(B1 + r, v);
      }
    }
    gridbar(bar, ++ph, grp);
  }

  // ================= decoder: 3 phases per step ===============================================
  for (int t = 0; t < SEQL; ++t) {
    // ---- Ph1: token select (redundant per block) + preact0(t) = Wih0d@x + B0 ----
    if (t == 0) {
      if (tid == 0) stok = BOSTOK;
    } else if (wv == 0) {
      float bv = -1e30f; int bi = 0;
#pragma unroll
      for (int j = 0; j < NBLK / 64; ++j) {
        int   idx = lane + 64 * j;
        float v   = gld(pmv + idx);
        int   i2  = gldi(pmi + idx);
        if (v > bv || (v == bv && i2 < bi)) { bv = v; bi = i2; }
      }
#pragma unroll
      for (int o = 32; o > 0; o >>= 1) {
        float v  = __shfl_xor(bv, o, 64);
        int   i2 = __shfl_xor(bi, o, 64);
        if (v > bv || (v == bv && i2 < bi)) { bv = v; bi = i2; }
      }
      if (lane == 0) stok = bi;
    }
    __syncthreads();
    sx[tid] = p.embD[(size_t)stok * HID + tid];
    __syncthreads();
    for (int it = gw; it < G4; it += TOTW) {
      float v = wsum(dotg(dW0i + (size_t)it * HID, sx, lane)) + gld(B0 + it);
      if (lane == 0) gst(pa0d + (t & 3) * G4 + it, v);
    }
    gridbar(bar, ++ph, grp);

    // ---- Ph2: h0d(t); preact1(t) = Wih1d@h0 + B1 ----
    derive(pa0d + (t & 3) * G4, c0d + (t & 3) * HID,
           b0 ? (c0d + ((t + 1) & 3) * HID) : nullptr, sh0, tid);
    __syncthreads();
    for (int it = gw; it < G4; it += TOTW) {
      float v = wsum(dotg(dW1i + (size_t)it * HID, sh0, lane)) + gld(B1 + it);
      if (lane == 0) gst(pa1d + (t & 3) * G4 + it, v);
    }
    gridbar(bar, ++ph, grp);

    // ---- Ph3: h1d(t); logits = outW@h1 + b (+argmax partials); B0/B1 for step t+1 ----
    derive(pa1d + (t & 3) * G4, c1d + (t & 3) * HID,
           b0 ? (c1d + ((t + 1) & 3) * HID) : nullptr, sh1, tid);
    __syncthreads();
    float bv = -1e30f; int bi = 0;
    if (p.useH) {
      // fp16 oW stream, 4 rows in flight per wave (8x uint4 loads / lane / iter)
      const float4* v4 = (const float4*)sh1;
      for (int base = 0; base < VOC; base += 4 * TOTW) {
        int r0 = base + gw;               // always < VOC (base <= 16384, gw < 4096)
        int r1 = r0 + TOTW, r2 = r1 + TOTW, r3 = r2 + TOTW;
        bool k3 = (r3 < VOC);             // only r3 can run off the end
        const uint4* w0 = (const uint4*)(oWh + (size_t)r0 * HID);
        const uint4* w1 = (const uint4*)(oWh + (size_t)r1 * HID);
        const uint4* w2 = (const uint4*)(oWh + (size_t)r2 * HID);
        const uint4* w3 = (const uint4*)(oWh + (size_t)(k3 ? r3 : r0) * HID);
        float a0 = 0.f, a1 = 0.f, a2 = 0.f, a3 = 0.f;
#pragma unroll
        for (int j = 0; j < 2; ++j) {
          int wi = lane + 64 * j;
          uint4 u0 = w0[wi], u1 = w1[wi], u2 = w2[wi], u3 = w3[wi];
          float4 bA = v4[2 * wi], bB = v4[2 * wi + 1];
          a0 += dot8(u0, bA, bB);
          a1 += dot8(u1, bA, bB);
          a2 += dot8(u2, bA, bB);
          a3 += dot8(u3, bA, bB);
        }
        a0 = wsum(a0); a1 = wsum(a1); a2 = wsum(a2); a3 = wsum(a3);
        float l0 = a0 + p.ob[r0], l1 = a1 + p.ob[r1], l2 = a2 + p.ob[r2];
        if (lane == 0) {
          gst(p.out + (size_t)t * VOC + r0, l0);
          gst(p.out + (size_t)t * VOC + r1, l1);
          gst(p.out + (size_t)t * VOC + r2, l2);
        }
        if (l0 > bv) { bv = l0; bi = r0; }
        if (l1 > bv) { bv = l1; bi = r1; }
        if (l2 > bv) { bv = l2; bi = r2; }
        if (k3) {
          float l3 = a3 + p.ob[r3];
          if (lane == 0) gst(p.out + (size_t)t * VOC + r3, l3);
          if (l3 > bv) { bv = l3; bi = r3; }
        }
      }
      for (int it = gw; it < 2 * G4; it += TOTW) {
        if (it < G4) {
          float v = wsum(dotg(dW0h + (size_t)it * HID, sh0, lane)) + db0i[it] + db0h[it];
          if (lane == 0) gst(B0 + it, v);
        } else {
          int r = it - G4;
          float v = wsum(dotg(dW1h + (size_t)r * HID, sh1, lane)) + db1i[r] + db1h[r];
          if (lane == 0) gst(B1 + r, v);
        }
      }
    } else {
      for (int it = gw; it < VOC + 2 * G4; it += TOTW) {
        if (it < VOC) {
          float v = wsum(dotg(p.oW + (size_t)it * HID, sh1, lane)) + p.ob[it];
          if (lane == 0) gst(p.out + (size_t)t * VOC + it, v);
          if (v > bv) { bv = v; bi = it; }
        } else if (it < VOC + G4) {
          int r = it - VOC;
          float v = wsum(dotg(dW0h + (size_t)r * HID, sh0, lane)) + db0i[r] + db0h[r];
          if (lane == 0) gst(B0 + r, v);
        } else {
          int r = it - VOC - G4;
          float v = wsum(dotg(dW1h + (size_t)r * HID, sh1, lane)) + db1i[r] + db1h[r];
          if (lane == 0) gst(B1 + r, v);
        }
      }
    }
    if (lane == 0) { rv[wv] = bv; ri[wv] = bi; }
    __syncthreads();
    if (tid == 0) {
      float v = rv[0]; int i2 = ri[0];
      for (int j = 1; j < NWAVES; ++j)
        if (rv[j] > v || (rv[j] == v && ri[j] < i2)) { v = rv[j]; i2 = ri[j]; }
      gst(pmv + blockIdx.x, v); gsti(pmi + blockIdx.x, i2);
    }
    gridbar(bar, ++ph, grp);
  }

  // ================= epilogue: log_softmax over each of 64 rows (4 blocks per row) ============
  {
    const int row = blockIdx.x >> 2;
    const int seg = blockIdx.x & 3;
    float* base = p.out + (size_t)row * VOC + (size_t)seg * 8000;

    float lm = -1e30f;
    for (int i = tid; i < 8000; i += NTHR) lm = fmaxf(lm, gld(base + i));
#pragma unroll
    for (int o = 32; o > 0; o >>= 1) lm = fmaxf(lm, __shfl_xor(lm, o, 64));
    if (lane == 0) rv[wv] = lm;
    __syncthreads();
    float bm = rv[0];
#pragma unroll
    for (int j = 1; j < NWAVES; ++j) bm = fmaxf(bm, rv[j]);
    float ls = 0.f;
    for (int i = tid; i < 8000; i += NTHR) ls += expf(gld(base + i) - bm);
    ls = wsum(ls);
    __syncthreads();
    if (lane == 0) rv[wv] = ls;
    __syncthreads();
    if (tid == 0) {
      float ss = 0.f;
      for (int j = 0; j < NWAVES; ++j) ss += rv[j];
      gst(lsep + blockIdx.x * 2,     bm);
      gst(lsep + blockIdx.x * 2 + 1, ss);
    }
    gridbar(bar, ++ph, grp);

    const float* lp = lsep + (size_t)row * 8;
    float l0 = gld(lp), l2 = gld(lp + 2), l4 = gld(lp + 4), l6 = gld(lp + 6);
    float s1 = gld(lp + 1), s3 = gld(lp + 3), s5 = gld(lp + 5), s7 = gld(lp + 7);
    float M = fmaxf(fmaxf(l0, l2), fmaxf(l4, l6));
    float S = s1 * expf(l0 - M) + s3 * expf(l2 - M) +
              s5 * expf(l4 - M) + s7 * expf(l6 - M);
    float L = M + logf(S);
    for (int i = tid; i < 8000; i += NTHR) base[i] = gld(base + i) - L;
  }
}

extern "C" void kernel_launch(void* const* d_in, const int* in_sizes, int n_in,
                              void* d_out, int out_size, void* d_ws, size_t ws_size,
                              hipStream_t stream) {
  P p;
  p.src  = (const int*)d_in[0];
  // d_in[1] = tgt (only its length matters; == SEQL)
  p.embE = (const float*)d_in[2];
  p.eWih = (const float*)d_in[3];
  p.eWhh = (const float*)d_in[4];
  p.ebih = (const float*)d_in[5];
  p.ebhh = (const float*)d_in[6];
  p.embD = (const float*)d_in[7];
  p.dWih = (const float*)d_in[8];
  p.dWhh = (const float*)d_in[9];
  p.dbih = (const float*)d_in[10];
  p.dbhh = (const float*)d_in[11];
  p.oW   = (const float*)d_in[12];
  p.ob   = (const float*)d_in[13];
  p.out  = (float*)d_out;
  p.ws   = (float*)d_ws;
  p.useH = (ws_size >= NEEDH) ? 1 : 0;

  hipLaunchKernelGGL(init_bar, dim3(1), dim3(256), 0, stream, (unsigned*)d_ws);
  void* args[] = { &p };
  hipLaunchCooperativeKernel((const void*)rnn_all, dim3(NBLK), dim3(NTHR), args, 0, stream);
}